// Round 9
// baseline (110.375 us; speedup 1.0000x reference)
//
#include <hip/hip_runtime.h>

#define DK 256   // feature dim (K)
#define TT 1024  // T1 = T2
#define NB 16    // batch

typedef __attribute__((ext_vector_type(8))) short bf16x8;
typedef __attribute__((ext_vector_type(4))) float f32x4;

// HW packed fp32->bf16 (RNE). r[15:0]=bf16(lo), r[31:16]=bf16(hi).
__device__ __forceinline__ unsigned int cvt_pk_bf16(float lo, float hi) {
    unsigned int r;
    asm("v_cvt_pk_bf16_f32 %0, %1, %2" : "=v"(r) : "v"(lo), "v"(hi));
    return r;
}

union BF8 { uint4 u; bf16x8 v; };

// ---------------------------------------------------------------------------
// R14 = R13 two-kernel split + Bs staging turned into pure global_load_lds
// DMA. R13 post-mortem: split reached 108.96 (new best); gemm's remaining
// non-essential work is the staging round-trip (4096 uint4 reg-loads +
// 4096 ds_writes per block). Since prep OWNS the yb layout, prep now writes
// yb PRE-SWIZZLED (chunk c at slot c^(j&7)) so gemm stages with linear
// global src -> linear LDS dest DMA (rule 21: permutation baked into the
// producer). Zero VGPR staging traffic; the single barrier drains the DMA.
//  * prep: yb write index now ((c^(r&7))*8 + half*4); xb/tx/ty unchanged.
//  * gemm: stage = 8 global_load_lds(16B) per wave; K-loop/epilogue as R13.
//  * Fallback fused kernel (R6) kept for ws_size < NEED.
// ---------------------------------------------------------------------------

// ---- kernel 1: convert + row-reduction prep ----
__global__ __launch_bounds__(256) void prep_kernel(
    const float* __restrict__ x, const float* __restrict__ y,
    const float* __restrict__ WS,
    unsigned short* __restrict__ xb, unsigned short* __restrict__ yb,
    float* __restrict__ tx, float* __restrict__ ty)
{
    const int lane = threadIdx.x & 63;
    const int gw   = blockIdx.x * 4 + (threadIdx.x >> 6); // wave 0..32767
    const int r    = gw & 16383;                          // row 0..16383
    const bool isx = gw < 16384;

    const float* src = (isx ? x : y) + (size_t)r * DK + lane * 4;
    const float4 v  = *(const float4*)src;
    const float4 wd = *(const float4*)(WS + (isx ? 0 : DK) + lane * 4);

    float dot = v.x * wd.x + v.y * wd.y + v.z * wd.z + v.w * wd.w;
    dot += __shfl_xor(dot, 1);
    dot += __shfl_xor(dot, 2);
    dot += __shfl_xor(dot, 4);
    dot += __shfl_xor(dot, 8);
    dot += __shfl_xor(dot, 16);
    dot += __shfl_xor(dot, 32);

    float4 s = v;
    if (!isx) {
        const float4 w3 = *(const float4*)(WS + 2 * DK + lane * 4);
        s.x = v.x * w3.x; s.y = v.y * w3.y; s.z = v.z * w3.z; s.w = v.w * w3.w;
    }
    uint2 o;
    o.x = cvt_pk_bf16(s.x, s.y);
    o.y = cvt_pk_bf16(s.z, s.w);

    if (isx) {
        // xb: plain row-major
        *(uint2*)(xb + (size_t)r * DK + lane * 4) = o;
    } else {
        // yb: PRE-SWIZZLED within the row so gemm can DMA-stage linearly.
        // lane covers chunk c = lane>>1 (16B = 8 elems), half h = lane&1.
        const int c = lane >> 1;
        const int h = lane & 1;
        *(uint2*)(yb + (size_t)r * DK + ((c ^ (r & 7)) * 8 + h * 4)) = o;
    }
    if (lane == 0) (isx ? tx : ty)[r] = dot;
}

// ---- kernel 2: bf16 GEMM + rank-1 additions; DMA-staged Bs ----
__global__ __launch_bounds__(512, 4) void gemm_kernel(
    const unsigned short* __restrict__ xb, const unsigned short* __restrict__ yb,
    const float* __restrict__ tx, const float* __restrict__ ty,
    float* __restrict__ out)
{
    __shared__ unsigned short Bs[128 * DK];   // 64 KB, swizzle baked by prep
    __shared__ float txs[256];
    __shared__ float tys[128];

    const int tid  = threadIdx.x;
    const int lane = tid & 63;
    const int w    = tid >> 6;                // wave 0..7

    // XCD-locality decode (as R6): id%8 constant across jt and is groups
    const int id = blockIdx.x;                // 0..511
    const int b  = id & 15;                   // batch
    const int is = (id >> 4) & 3;             // i slice (0..3), 256 rows
    const int jt = id >> 6;                   // j tile (0..7), 128 cols

    // ---- 1. stage Bs via global_load_lds (linear both sides; swizzle is
    //         already baked into yb's layout by prep)
    {
        const unsigned short* gY = yb + ((size_t)b * TT + jt * 128) * DK;
        #pragma unroll
        for (int it = 0; it < 8; ++it) {
            const int g = it * 512 + w * 64 + lane;       // 16B chunk 0..4095
            const unsigned short* gp = gY + (size_t)g * 8;        // per-lane
            unsigned short* lp = Bs + (size_t)(it * 512 + w * 64) * 8; // uniform
            __builtin_amdgcn_global_load_lds(
                (const __attribute__((address_space(1))) void*)gp,
                (__attribute__((address_space(3))) void*)lp, 16, 0, 0);
        }
        if (tid < 64)
            *(float4*)&txs[tid * 4] =
                *(const float4*)(tx + b * TT + is * 256 + tid * 4);
        else if (tid < 96)
            *(float4*)&tys[(tid - 64) * 4] =
                *(const float4*)(ty + b * TT + jt * 128 + (tid - 64) * 4);
    }
    __syncthreads();              // drains DMA (vmcnt 0) + publishes txs/tys

    // ---- 2. K-loop: A-frags direct from global bf16, no conversion
    const int mfr  = lane & 15;
    const int quad = lane >> 4;
    const int i0   = is * 256 + w * 32;
    const unsigned short* gA = xb + ((size_t)b * TT + i0) * DK;

    f32x4 acc[2][8];
    #pragma unroll
    for (int it = 0; it < 2; ++it)
        #pragma unroll
        for (int n = 0; n < 8; ++n)
            acc[it][n] = (f32x4){0.f, 0.f, 0.f, 0.f};

    #pragma unroll
    for (int ks = 0; ks < 8; ++ks) {
        bf16x8 av[2];
        #pragma unroll
        for (int it = 0; it < 2; ++it) {
            BF8 cv;
            cv.u = *(const uint4*)(gA + (size_t)(it * 16 + mfr) * DK
                                   + ks * 32 + quad * 8);
            av[it] = cv.v;
        }
        #pragma unroll
        for (int n = 0; n < 8; ++n) {
            const int j    = n * 16 + mfr;
            const int slot = (ks * 4 + quad) ^ (j & 7);
            const bf16x8 bv = *(const bf16x8*)(Bs + j * DK + slot * 8);
            #pragma unroll
            for (int it = 0; it < 2; ++it)
                acc[it][n] = __builtin_amdgcn_mfma_f32_16x16x32_bf16(
                    av[it], bv, acc[it][n], 0, 0, 0);
        }
    }

    // ---- 3. epilogue: + tx[i] + ty[j] from LDS, fp32 stores
    float tyv[8];
    #pragma unroll
    for (int n = 0; n < 8; ++n)
        tyv[n] = tys[n * 16 + mfr];

    float* outB = out + ((size_t)b << 20) + (size_t)i0 * TT + jt * 128;
    #pragma unroll
    for (int it = 0; it < 2; ++it) {
        #pragma unroll
        for (int r = 0; r < 4; ++r) {
            const int row  = it * 16 + quad * 4 + r;
            const float trow = txs[w * 32 + row];
            #pragma unroll
            for (int n = 0; n < 8; ++n)
                outB[(size_t)row * TT + n * 16 + mfr] =
                    acc[it][n][r] + trow + tyv[n];
        }
    }
}

// ---- fallback: exact R6 fused kernel (used only if ws is too small) ----
__global__ __launch_bounds__(512, 4) void fused_kernel(
    const float* __restrict__ x, const float* __restrict__ y,
    const float* __restrict__ WS, float* __restrict__ out)
{
    __shared__ unsigned short Bs[128 * DK];
    __shared__ float tys[128];

    const int tid  = threadIdx.x;
    const int lane = tid & 63;
    const int w    = tid >> 6;

    const int id = blockIdx.x;
    const int b  = id & 15;
    const int is = (id >> 4) & 3;
    const int jt = id >> 6;

    {
        const float* gY0 = y + ((size_t)b * TT + jt * 128) * DK;
        const int c = tid & 31;
        const float* w3p = WS + 2 * DK + c * 8;
        const float* w2p = WS + DK + c * 8;
        const float4 wa = *(const float4*)(w3p);
        const float4 wb = *(const float4*)(w3p + 4);
        const float4 va = *(const float4*)(w2p);
        const float4 vb = *(const float4*)(w2p + 4);
        #pragma unroll
        for (int it = 0; it < 8; ++it) {
            const int j = it * 16 + (tid >> 5);
            const float* gY = gY0 + (size_t)j * DK + c * 8;
            const float4 ya = *(const float4*)(gY);
            const float4 yb2 = *(const float4*)(gY + 4);
            float p = ya.x * va.x + ya.y * va.y + ya.z * va.z + ya.w * va.w
                    + yb2.x * vb.x + yb2.y * vb.y + yb2.z * vb.z + yb2.w * vb.w;
            uint4 o;
            o.x = cvt_pk_bf16(ya.x * wa.x, ya.y * wa.y);
            o.y = cvt_pk_bf16(ya.z * wa.z, ya.w * wa.w);
            o.z = cvt_pk_bf16(yb2.x * wb.x, yb2.y * wb.y);
            o.w = cvt_pk_bf16(yb2.z * wb.z, yb2.w * wb.w);
            const int slot = c ^ (j & 7);
            *(uint4*)(Bs + j * DK + slot * 8) = o;
            p += __shfl_xor(p, 1);
            p += __shfl_xor(p, 2);
            p += __shfl_xor(p, 4);
            p += __shfl_xor(p, 8);
            p += __shfl_xor(p, 16);
            if ((tid & 31) == 0) tys[j] = p;
        }
    }
    __syncthreads();

    const int mfr  = lane & 15;
    const int quad = lane >> 4;
    const int i0   = is * 256 + w * 32;
    const float* gA = x + ((size_t)b * TT + i0) * DK;

    f32x4 acc[2][8];
    #pragma unroll
    for (int it = 0; it < 2; ++it)
        #pragma unroll
        for (int n = 0; n < 8; ++n)
            acc[it][n] = (f32x4){0.f, 0.f, 0.f, 0.f};
    float txp[2] = {0.f, 0.f};

    #pragma unroll
    for (int ks = 0; ks < 8; ++ks) {
        const float* w1p = WS + ks * 32 + quad * 8;
        const float4 w1a = *(const float4*)(w1p);
        const float4 w1b = *(const float4*)(w1p + 4);
        bf16x8 av[2];
        #pragma unroll
        for (int it = 0; it < 2; ++it) {
            const float* rp = gA + (size_t)(it * 16 + mfr) * DK
                              + ks * 32 + quad * 8;
            const float4 xa = *(const float4*)rp;
            const float4 xb2 = *(const float4*)(rp + 4);
            txp[it] += xa.x * w1a.x + xa.y * w1a.y + xa.z * w1a.z + xa.w * w1a.w
                     + xb2.x * w1b.x + xb2.y * w1b.y + xb2.z * w1b.z + xb2.w * w1b.w;
            BF8 cv;
            cv.u.x = cvt_pk_bf16(xa.x, xa.y);
            cv.u.y = cvt_pk_bf16(xa.z, xa.w);
            cv.u.z = cvt_pk_bf16(xb2.x, xb2.y);
            cv.u.w = cvt_pk_bf16(xb2.z, xb2.w);
            av[it] = cv.v;
        }
        #pragma unroll
        for (int n = 0; n < 8; ++n) {
            const int j    = n * 16 + mfr;
            const int slot = (ks * 4 + quad) ^ (j & 7);
            const bf16x8 bv = *(const bf16x8*)(Bs + j * DK + slot * 8);
            #pragma unroll
            for (int it = 0; it < 2; ++it)
                acc[it][n] = __builtin_amdgcn_mfma_f32_16x16x32_bf16(
                    av[it], bv, acc[it][n], 0, 0, 0);
        }
    }

    #pragma unroll
    for (int it = 0; it < 2; ++it) {
        txp[it] += __shfl_xor(txp[it], 16);
        txp[it] += __shfl_xor(txp[it], 32);
    }

    float tyv[8];
    #pragma unroll
    for (int n = 0; n < 8; ++n)
        tyv[n] = tys[n * 16 + mfr];

    float* outB = out + ((size_t)b << 20) + (size_t)i0 * TT + jt * 128;
    #pragma unroll
    for (int it = 0; it < 2; ++it) {
        #pragma unroll
        for (int r = 0; r < 4; ++r) {
            const int row = it * 16 + quad * 4 + r;
            const float trow = __shfl(txp[it], (lane & 48) | (quad * 4 + r));
            #pragma unroll
            for (int n = 0; n < 8; ++n)
                outB[(size_t)row * TT + n * 16 + mfr] =
                    acc[it][n][r] + trow + tyv[n];
        }
    }
}

extern "C" void kernel_launch(void* const* d_in, const int* in_sizes, int n_in,
                              void* d_out, int out_size, void* d_ws, size_t ws_size,
                              hipStream_t stream)
{
    const float* x  = (const float*)d_in[0];
    const float* y  = (const float*)d_in[1];
    const float* WS = (const float*)d_in[2];
    float* out = (float*)d_out;

    // ws layout (bytes): xb[8388608] | yb[8388608] | tx[65536] | ty[65536]
    const size_t XB_OFF = 0;
    const size_t YB_OFF = 8388608;
    const size_t TX_OFF = 16777216;
    const size_t TY_OFF = 16842752;
    const size_t NEED   = 16908288;

    if (ws_size >= NEED && d_ws != nullptr) {
        unsigned short* xb = (unsigned short*)((char*)d_ws + XB_OFF);
        unsigned short* yb = (unsigned short*)((char*)d_ws + YB_OFF);
        float* tx = (float*)((char*)d_ws + TX_OFF);
        float* ty = (float*)((char*)d_ws + TY_OFF);
        prep_kernel<<<dim3(8192), dim3(256), 0, stream>>>(x, y, WS, xb, yb, tx, ty);
        gemm_kernel<<<dim3(512), dim3(512), 0, stream>>>(xb, yb, tx, ty, out);
    } else {
        fused_kernel<<<dim3(512), dim3(512), 0, stream>>>(x, y, WS, out);
    }
}

// Round 10
// 108.056 us; speedup vs baseline: 1.0215x; 1.0215x over previous
//
#include <hip/hip_runtime.h>

#define DK 256   // feature dim (K)
#define TT 1024  // T1 = T2
#define NB 16    // batch

typedef __attribute__((ext_vector_type(8))) short bf16x8;
typedef __attribute__((ext_vector_type(4))) float f32x4;

// HW packed fp32->bf16 (RNE). r[15:0]=bf16(lo), r[31:16]=bf16(hi).
__device__ __forceinline__ unsigned int cvt_pk_bf16(float lo, float hi) {
    unsigned int r;
    asm("v_cvt_pk_bf16_f32 %0, %1, %2" : "=v"(r) : "v"(lo), "v"(hi));
    return r;
}

union BF8 { uint4 u; bf16x8 v; };

// ---------------------------------------------------------------------------
// R15 = R14 + registered A-window (the R9 idea, now affordable).
// R14 post-mortem: DMA-staged Bs neutral -> staging wasn't the cost; the
// gemm still pays the per-iter global-A-load latency chain (the same chain
// every fused variant paid). R9/R10 failed because fp32 window (128 VGPR)
// + 64 AGPR acc spilled. Post-split A is bf16 (half regs) and Bs staging
// is DMA (zero regs), so a 4-step window fits (512,4)'s 128-reg cap:
//  * uint4 a[4][2] (32 VGPR): ks0-3 issued BEFORE the stage phase (8
//    independent loads/thread in flight; one barrier drain covers all).
//  * In-loop dist-4 reload: after consuming a[ks&3], load ks+4 into it.
//    ~4 iters (~800cy) issue-to-use distance >= L3 latency. Compile-time
//    indices only (rule #20).
//  * K-loop now: ds_read + MFMA only, zero unhidden global latency.
//  * Budget 32+64+~30 ~= 126 <= 128. Spill tripwire: WRITE_SIZE > 75MB.
//  * prep / fallback unchanged from R14 (yb pre-swizzle verified).
// ---------------------------------------------------------------------------

// ---- kernel 1: convert + row-reduction prep ----
__global__ __launch_bounds__(256) void prep_kernel(
    const float* __restrict__ x, const float* __restrict__ y,
    const float* __restrict__ WS,
    unsigned short* __restrict__ xb, unsigned short* __restrict__ yb,
    float* __restrict__ tx, float* __restrict__ ty)
{
    const int lane = threadIdx.x & 63;
    const int gw   = blockIdx.x * 4 + (threadIdx.x >> 6); // wave 0..32767
    const int r    = gw & 16383;                          // row 0..16383
    const bool isx = gw < 16384;

    const float* src = (isx ? x : y) + (size_t)r * DK + lane * 4;
    const float4 v  = *(const float4*)src;
    const float4 wd = *(const float4*)(WS + (isx ? 0 : DK) + lane * 4);

    float dot = v.x * wd.x + v.y * wd.y + v.z * wd.z + v.w * wd.w;
    dot += __shfl_xor(dot, 1);
    dot += __shfl_xor(dot, 2);
    dot += __shfl_xor(dot, 4);
    dot += __shfl_xor(dot, 8);
    dot += __shfl_xor(dot, 16);
    dot += __shfl_xor(dot, 32);

    float4 s = v;
    if (!isx) {
        const float4 w3 = *(const float4*)(WS + 2 * DK + lane * 4);
        s.x = v.x * w3.x; s.y = v.y * w3.y; s.z = v.z * w3.z; s.w = v.w * w3.w;
    }
    uint2 o;
    o.x = cvt_pk_bf16(s.x, s.y);
    o.y = cvt_pk_bf16(s.z, s.w);

    if (isx) {
        // xb: plain row-major
        *(uint2*)(xb + (size_t)r * DK + lane * 4) = o;
    } else {
        // yb: PRE-SWIZZLED within the row so gemm can DMA-stage linearly.
        const int c = lane >> 1;
        const int h = lane & 1;
        *(uint2*)(yb + (size_t)r * DK + ((c ^ (r & 7)) * 8 + h * 4)) = o;
    }
    if (lane == 0) (isx ? tx : ty)[r] = dot;
}

// ---- kernel 2: bf16 GEMM + rank-1 additions; DMA Bs + A-window ----
__global__ __launch_bounds__(512, 4) void gemm_kernel(
    const unsigned short* __restrict__ xb, const unsigned short* __restrict__ yb,
    const float* __restrict__ tx, const float* __restrict__ ty,
    float* __restrict__ out)
{
    __shared__ unsigned short Bs[128 * DK];   // 64 KB, swizzle baked by prep
    __shared__ float txs[256];
    __shared__ float tys[128];

    const int tid  = threadIdx.x;
    const int lane = tid & 63;
    const int w    = tid >> 6;                // wave 0..7

    // XCD-locality decode (as R6): id%8 constant across jt and is groups
    const int id = blockIdx.x;                // 0..511
    const int b  = id & 15;                   // batch
    const int is = (id >> 4) & 3;             // i slice (0..3), 256 rows
    const int jt = id >> 6;                   // j tile (0..7), 128 cols

    const int mfr  = lane & 15;
    const int quad = lane >> 4;
    const int i0   = is * 256 + w * 32;
    const unsigned short* gA = xb + ((size_t)b * TT + i0) * DK;

    // ---- 0. A-window: issue ks=0..3 loads first (8 independent per thread)
    uint4 a[4][2];
    #pragma unroll
    for (int ks = 0; ks < 4; ++ks)
        #pragma unroll
        for (int it = 0; it < 2; ++it)
            a[ks][it] = *(const uint4*)(gA + (size_t)(it * 16 + mfr) * DK
                                        + ks * 32 + quad * 8);

    // ---- 1. stage Bs via global_load_lds (swizzle baked in yb by prep)
    {
        const unsigned short* gY = yb + ((size_t)b * TT + jt * 128) * DK;
        #pragma unroll
        for (int it = 0; it < 8; ++it) {
            const int g = it * 512 + w * 64 + lane;       // 16B chunk 0..4095
            const unsigned short* gp = gY + (size_t)g * 8;        // per-lane
            unsigned short* lp = Bs + (size_t)(it * 512 + w * 64) * 8; // uniform
            __builtin_amdgcn_global_load_lds(
                (const __attribute__((address_space(1))) void*)gp,
                (__attribute__((address_space(3))) void*)lp, 16, 0, 0);
        }
        if (tid < 64)
            *(float4*)&txs[tid * 4] =
                *(const float4*)(tx + b * TT + is * 256 + tid * 4);
        else if (tid < 96)
            *(float4*)&tys[(tid - 64) * 4] =
                *(const float4*)(ty + b * TT + jt * 128 + (tid - 64) * 4);
    }
    __syncthreads();     // one drain covers DMA + the 8 A-window loads

    // ---- 2. K-loop: pure LDS+MFMA, dist-4 A reload
    f32x4 acc[2][8];
    #pragma unroll
    for (int it = 0; it < 2; ++it)
        #pragma unroll
        for (int n = 0; n < 8; ++n)
            acc[it][n] = (f32x4){0.f, 0.f, 0.f, 0.f};

    #pragma unroll
    for (int ks = 0; ks < 8; ++ks) {
        bf16x8 av[2];
        #pragma unroll
        for (int it = 0; it < 2; ++it) {
            BF8 cv;
            cv.u = a[ks & 3][it];
            av[it] = cv.v;
        }
        // dist-4 reload into the consumed slot (compile-time indices)
        if (ks < 4) {
            #pragma unroll
            for (int it = 0; it < 2; ++it)
                a[ks & 3][it] = *(const uint4*)(gA
                    + (size_t)(it * 16 + mfr) * DK + (ks + 4) * 32 + quad * 8);
        }
        #pragma unroll
        for (int n = 0; n < 8; ++n) {
            const int j    = n * 16 + mfr;
            const int slot = (ks * 4 + quad) ^ (j & 7);
            const bf16x8 bv = *(const bf16x8*)(Bs + j * DK + slot * 8);
            #pragma unroll
            for (int it = 0; it < 2; ++it)
                acc[it][n] = __builtin_amdgcn_mfma_f32_16x16x32_bf16(
                    av[it], bv, acc[it][n], 0, 0, 0);
        }
    }

    // ---- 3. epilogue: + tx[i] + ty[j] from LDS, fp32 stores
    float tyv[8];
    #pragma unroll
    for (int n = 0; n < 8; ++n)
        tyv[n] = tys[n * 16 + mfr];

    float* outB = out + ((size_t)b << 20) + (size_t)i0 * TT + jt * 128;
    #pragma unroll
    for (int it = 0; it < 2; ++it) {
        #pragma unroll
        for (int r = 0; r < 4; ++r) {
            const int row  = it * 16 + quad * 4 + r;
            const float trow = txs[w * 32 + row];
            #pragma unroll
            for (int n = 0; n < 8; ++n)
                outB[(size_t)row * TT + n * 16 + mfr] =
                    acc[it][n][r] + trow + tyv[n];
        }
    }
}

// ---- fallback: exact R6 fused kernel (used only if ws is too small) ----
__global__ __launch_bounds__(512, 4) void fused_kernel(
    const float* __restrict__ x, const float* __restrict__ y,
    const float* __restrict__ WS, float* __restrict__ out)
{
    __shared__ unsigned short Bs[128 * DK];
    __shared__ float tys[128];

    const int tid  = threadIdx.x;
    const int lane = tid & 63;
    const int w    = tid >> 6;

    const int id = blockIdx.x;
    const int b  = id & 15;
    const int is = (id >> 4) & 3;
    const int jt = id >> 6;

    {
        const float* gY0 = y + ((size_t)b * TT + jt * 128) * DK;
        const int c = tid & 31;
        const float* w3p = WS + 2 * DK + c * 8;
        const float* w2p = WS + DK + c * 8;
        const float4 wa = *(const float4*)(w3p);
        const float4 wb = *(const float4*)(w3p + 4);
        const float4 va = *(const float4*)(w2p);
        const float4 vb = *(const float4*)(w2p + 4);
        #pragma unroll
        for (int it = 0; it < 8; ++it) {
            const int j = it * 16 + (tid >> 5);
            const float* gY = gY0 + (size_t)j * DK + c * 8;
            const float4 ya = *(const float4*)(gY);
            const float4 yb2 = *(const float4*)(gY + 4);
            float p = ya.x * va.x + ya.y * va.y + ya.z * va.z + ya.w * va.w
                    + yb2.x * vb.x + yb2.y * vb.y + yb2.z * vb.z + yb2.w * vb.w;
            uint4 o;
            o.x = cvt_pk_bf16(ya.x * wa.x, ya.y * wa.y);
            o.y = cvt_pk_bf16(ya.z * wa.z, ya.w * wa.w);
            o.z = cvt_pk_bf16(yb2.x * wb.x, yb2.y * wb.y);
            o.w = cvt_pk_bf16(yb2.z * wb.z, yb2.w * wb.w);
            const int slot = c ^ (j & 7);
            *(uint4*)(Bs + j * DK + slot * 8) = o;
            p += __shfl_xor(p, 1);
            p += __shfl_xor(p, 2);
            p += __shfl_xor(p, 4);
            p += __shfl_xor(p, 8);
            p += __shfl_xor(p, 16);
            if ((tid & 31) == 0) tys[j] = p;
        }
    }
    __syncthreads();

    const int mfr  = lane & 15;
    const int quad = lane >> 4;
    const int i0   = is * 256 + w * 32;
    const float* gA = x + ((size_t)b * TT + i0) * DK;

    f32x4 acc[2][8];
    #pragma unroll
    for (int it = 0; it < 2; ++it)
        #pragma unroll
        for (int n = 0; n < 8; ++n)
            acc[it][n] = (f32x4){0.f, 0.f, 0.f, 0.f};
    float txp[2] = {0.f, 0.f};

    #pragma unroll
    for (int ks = 0; ks < 8; ++ks) {
        const float* w1p = WS + ks * 32 + quad * 8;
        const float4 w1a = *(const float4*)(w1p);
        const float4 w1b = *(const float4*)(w1p + 4);
        bf16x8 av[2];
        #pragma unroll
        for (int it = 0; it < 2; ++it) {
            const float* rp = gA + (size_t)(it * 16 + mfr) * DK
                              + ks * 32 + quad * 8;
            const float4 xa = *(const float4*)rp;
            const float4 xb2 = *(const float4*)(rp + 4);
            txp[it] += xa.x * w1a.x + xa.y * w1a.y + xa.z * w1a.z + xa.w * w1a.w
                     + xb2.x * w1b.x + xb2.y * w1b.y + xb2.z * w1b.z + xb2.w * w1b.w;
            BF8 cv;
            cv.u.x = cvt_pk_bf16(xa.x, xa.y);
            cv.u.y = cvt_pk_bf16(xa.z, xa.w);
            cv.u.z = cvt_pk_bf16(xb2.x, xb2.y);
            cv.u.w = cvt_pk_bf16(xb2.z, xb2.w);
            av[it] = cv.v;
        }
        #pragma unroll
        for (int n = 0; n < 8; ++n) {
            const int j    = n * 16 + mfr;
            const int slot = (ks * 4 + quad) ^ (j & 7);
            const bf16x8 bv = *(const bf16x8*)(Bs + j * DK + slot * 8);
            #pragma unroll
            for (int it = 0; it < 2; ++it)
                acc[it][n] = __builtin_amdgcn_mfma_f32_16x16x32_bf16(
                    av[it], bv, acc[it][n], 0, 0, 0);
        }
    }

    #pragma unroll
    for (int it = 0; it < 2; ++it) {
        txp[it] += __shfl_xor(txp[it], 16);
        txp[it] += __shfl_xor(txp[it], 32);
    }

    float tyv[8];
    #pragma unroll
    for (int n = 0; n < 8; ++n)
        tyv[n] = tys[n * 16 + mfr];

    float* outB = out + ((size_t)b << 20) + (size_t)i0 * TT + jt * 128;
    #pragma unroll
    for (int it = 0; it < 2; ++it) {
        #pragma unroll
        for (int r = 0; r < 4; ++r) {
            const int row = it * 16 + quad * 4 + r;
            const float trow = __shfl(txp[it], (lane & 48) | (quad * 4 + r));
            #pragma unroll
            for (int n = 0; n < 8; ++n)
                outB[(size_t)row * TT + n * 16 + mfr] =
                    acc[it][n][r] + trow + tyv[n];
        }
    }
}

extern "C" void kernel_launch(void* const* d_in, const int* in_sizes, int n_in,
                              void* d_out, int out_size, void* d_ws, size_t ws_size,
                              hipStream_t stream)
{
    const float* x  = (const float*)d_in[0];
    const float* y  = (const float*)d_in[1];
    const float* WS = (const float*)d_in[2];
    float* out = (float*)d_out;

    // ws layout (bytes): xb[8388608] | yb[8388608] | tx[65536] | ty[65536]
    const size_t XB_OFF = 0;
    const size_t YB_OFF = 8388608;
    const size_t TX_OFF = 16777216;
    const size_t TY_OFF = 16842752;
    const size_t NEED   = 16908288;

    if (ws_size >= NEED && d_ws != nullptr) {
        unsigned short* xb = (unsigned short*)((char*)d_ws + XB_OFF);
        unsigned short* yb = (unsigned short*)((char*)d_ws + YB_OFF);
        float* tx = (float*)((char*)d_ws + TX_OFF);
        float* ty = (float*)((char*)d_ws + TY_OFF);
        prep_kernel<<<dim3(8192), dim3(256), 0, stream>>>(x, y, WS, xb, yb, tx, ty);
        gemm_kernel<<<dim3(512), dim3(512), 0, stream>>>(xb, yb, tx, ty, out);
    } else {
        fused_kernel<<<dim3(512), dim3(512), 0, stream>>>(x, y, WS, out);
    }
}